// Round 1
// baseline (490.399 us; speedup 1.0000x reference)
//
#include <hip/hip_runtime.h>

#define NPIX (512*512)

typedef __attribute__((ext_vector_type(8))) short short8;   // 8 bf16 in 4 VGPRs
typedef __attribute__((ext_vector_type(4))) float f32x4;    // MFMA accumulator

#define MFMA16(A, B, C) __builtin_amdgcn_mfma_f32_16x16x32_bf16((A), (B), (C), 0, 0, 0)

// JAX gelu(approximate=True): x * sigmoid(2*sqrt(2/pi)*(x+0.044715x^3)); inf-safe.
__device__ __forceinline__ float gelu_f(float x) {
    return x / (1.0f + __expf(-1.5957691216057308f * (x + 0.044715f * x * x * x)));
}

// f32 -> bf16 bits (RNE)
__device__ __forceinline__ unsigned short bf16_rne(float x) {
    unsigned int b = __float_as_uint(x);
    unsigned int r = b + 0x7fffu + ((b >> 16) & 1u);
    return (unsigned short)(r >> 16);
}
__device__ __forceinline__ float bf16_tof(unsigned short h) {
    return __uint_as_float(((unsigned int)h) << 16);
}
__device__ __forceinline__ unsigned int bf16_split_pack(float x) {
    unsigned short hi = bf16_rne(x);
    unsigned short lo = bf16_rne(x - bf16_tof(hi));
    return (unsigned int)hi | ((unsigned int)lo << 16);
}
// unzip 8 split-packed u32 (hi|lo<<16 per elem) -> hi-short8 / lo-short8
__device__ __forceinline__ void unzip8(const unsigned int* w, short8& h, short8& l) {
    union { unsigned int u[4]; short8 v; } hh, ll;
    #pragma unroll
    for (int i = 0; i < 4; ++i) {
        hh.u[i] = (w[2*i] & 0xffffu) | (w[2*i+1] << 16);
        ll.u[i] = (w[2*i] >> 16) | (w[2*i+1] & 0xffff0000u);
    }
    h = hh.v; l = ll.v;
}

#define ASLAB ((size_t)16 * 4 * 2 * 64 * 48)   // shorts per (l,ax) in Am

// ---------------------------------------------------------------------------
// Merged setup + encoder: blocks 0..15 basis tables, 16..31 FFN weights,
// 32..287 spectral A-weights, 288..1311 encoder (h stored bf16).
// ---------------------------------------------------------------------------
__global__ __launch_bounds__(256) void k_setup(const float* __restrict__ W1, const float* __restrict__ W2,
                                               const float* __restrict__ Are, const float* __restrict__ Aim,
                                               const float* __restrict__ u, const float* __restrict__ xc,
                                               const float* __restrict__ We, const float* __restrict__ be,
                                               short* __restrict__ FbB, short* __restrict__ GbF,
                                               short* __restrict__ Wpk, short* __restrict__ Am,
                                               unsigned short* __restrict__ h) {
    int b = blockIdx.x;
    int t = threadIdx.x;
    if (b < 16) {
        int id = b * 256 + t;
        int lane = id & 63;
        int quad = lane >> 4, l15 = lane & 15;
        short* dst;
        int n0, nstep, o0, ostep;
        float wscale = 1.0f;
        if (id < 2048) {
            int nt = (id >> 6) & 1, kc = id >> 7;
            dst = FbB + id * 16;
            n0 = kc * 32 + quad * 8; nstep = 1;
            o0 = nt * 16 + l15;      ostep = 0;
        } else {
            int id2 = id - 2048;
            dst = GbF + id2 * 16;
            int tt = id2 >> 6;
            n0 = tt * 16 + l15;      nstep = 0;
            o0 = quad * 8;           ostep = 1;
            wscale = 1.0f / 512.0f;
        }
        #pragma unroll
        for (int j = 0; j < 8; ++j) {
            int n = n0 + nstep * j;
            int o = o0 + ostep * j;
            int m = o >> 1, ri = o & 1;
            int k = (n * m) & 511;
            float sv, cv;
            sincosf(6.283185307179586f * (1.0f / 512.0f) * (float)k, &sv, &cv);
            float v = ri ? -sv : cv;
            if (id >= 2048) v *= (m == 0 ? 1.0f : 2.0f) * wscale;
            unsigned short hi = bf16_rne(v);
            dst[j]     = (short)hi;
            dst[8 + j] = (short)bf16_rne(v - bf16_tof(hi));
        }
    } else if (b < 32) {
        int tid = (b - 16) * 256 + t;
        int lane = tid & 63;
        int kc = (tid >> 6) & 1;
        int mt = (tid >> 7) & 3;
        int wg = tid >> 9;
        int layer = wg >> 1, which = wg & 1;
        const float* Wsrc = (which ? W2 : W1) + (size_t)layer * 4096;
        int o  = mt * 16 + (lane & 15);
        int c0 = kc * 32 + ((lane >> 4) & 3) * 8;
        short* dst = Wpk + (size_t)tid * 16;
        #pragma unroll
        for (int j = 0; j < 8; ++j) {
            float x = Wsrc[o * 64 + c0 + j];
            unsigned short hi = bf16_rne(x);
            dst[j]     = (short)hi;
            dst[8 + j] = (short)bf16_rne(x - bf16_tof(hi));
        }
    } else if (b < 288) {
        int id = (b - 32) * 256 + t;
        int lane = id & 63;
        int kc  = (id >> 6) & 1;
        int mt  = (id >> 7) & 3;
        int m   = (id >> 9) & 15;
        int lax = id >> 13;
        int l = lax >> 1, ax = lax & 1;
        int o  = mt * 16 + (lane & 15);
        int i0 = kc * 32 + ((lane >> 4) & 3) * 8;
        short* dst = Am + (size_t)id * 48;
        #pragma unroll
        for (int j = 0; j < 8; ++j) {
            size_t src = (((size_t)(l * 64 + o) * 64 + (i0 + j)) * 16 + m) * 2 + ax;
            float ar = Are[src], ai = Aim[src];
            unsigned short hh;
            hh = bf16_rne(ar);  dst[j]      = (short)hh; dst[8 + j]  = (short)bf16_rne(ar - bf16_tof(hh));
            hh = bf16_rne(ai);  dst[16 + j] = (short)hh; dst[24 + j] = (short)bf16_rne(ai - bf16_tof(hh));
            hh = bf16_rne(-ai); dst[32 + j] = (short)hh; dst[40 + j] = (short)bf16_rne(-ai - bf16_tof(hh));
        }
    } else {
        // encoder: h[p][pix] = bf16(We.x + be)
        int pix = (b - 288) * 256 + t;
        float x0 = xc[pix], x1 = xc[NPIX + pix], uu = u[pix];
        #pragma unroll 8
        for (int p = 0; p < 64; ++p) {
            float v = We[p * 3] * x0 + We[p * 3 + 1] * x1 + We[p * 3 + 2] * uu + be[p];
            h[(size_t)p * NPIX + pix] = bf16_rne(v);
        }
    }
}

// ---------------------------------------------------------------------------
// Merged forward DFT, both axes, h in bf16 (B-frag direct reinterpret; A-side
// basis split -> 2-term MFMA). grid(64 p, 8 ntile, 2 axis).
// ---------------------------------------------------------------------------
__global__ __launch_bounds__(256) void k_fwd(const unsigned short* __restrict__ h, const short* __restrict__ FbB,
                                             float* __restrict__ VfH, float* __restrict__ VfW) {
    int t = threadIdx.x;
    int p = blockIdx.x, ntb = blockIdx.y, axis = blockIdx.z;
    int wv = t >> 6, lane = t & 63, quad = lane >> 4, l15 = lane & 15;
    int n = ntb * 64 + wv * 16 + l15;
    f32x4 acc[2];
    acc[0] = (f32x4){0.f,0.f,0.f,0.f}; acc[1] = (f32x4){0.f,0.f,0.f,0.f};
    #pragma unroll 4
    for (int kc = 0; kc < 16; ++kc) {
        int kb = kc * 32 + quad * 8;
        short8 Bv;
        if (axis == 0) {
            const unsigned short* hp = h + ((size_t)p * 512 + kb) * 512 + n;
            #pragma unroll
            for (int j = 0; j < 8; ++j) Bv[j] = (short)hp[(size_t)j * 512];
        } else {
            const unsigned short* hp = h + ((size_t)p * 512 + n) * 512 + kb;
            Bv = *(const short8*)hp;
        }
        #pragma unroll
        for (int mt = 0; mt < 2; ++mt) {
            const short8* ap = (const short8*)(FbB + (((kc * 2 + mt) * 64 + lane) << 4));
            short8 Ah = ap[0], Al = ap[1];
            acc[mt] = MFMA16(Ah, Bv, acc[mt]);
            acc[mt] = MFMA16(Al, Bv, acc[mt]);
        }
    }
    float* vp = (axis ? VfW : VfH) + (size_t)p * 32 * 512;
    #pragma unroll
    for (int mt = 0; mt < 2; ++mt)
        #pragma unroll
        for (int r = 0; r < 4; ++r)
            vp[(size_t)(mt * 16 + quad * 4 + r) * 512 + n] = acc[mt][r];
}

// ---------------------------------------------------------------------------
// Merged mode mixing, both axes. Epilogue writes Vm SPLIT-PACKED u32.
// grid 512 (axis = bid>>8; m = bid&15, otile = (bid>>4)&15), block 256.
// ---------------------------------------------------------------------------
__global__ __launch_bounds__(256) void k_mix2(const float* __restrict__ VfH, const float* __restrict__ VfW,
                                              const short* __restrict__ AmL,
                                              unsigned int* __restrict__ VmH, unsigned int* __restrict__ VmW) {
    __shared__ unsigned int BT[2 * 64 * 33];
    int bid = blockIdx.x;
    int axis = bid >> 8;
    int m  = bid & 15;
    int ot = (bid >> 4) & 15;
    const float* Vf = axis ? VfW : VfH;
    unsigned int* Vm = axis ? VmW : VmH;
    const short* Am = AmL + (size_t)axis * ASLAB;
    int t = threadIdx.x;
    #pragma unroll
    for (int it = 0; it < 16; ++it) {
        int idx = it * 256 + t;
        int oth = idx & 31, ri = (idx >> 5) & 1, i = idx >> 6;
        float v = Vf[((size_t)i * 32 + m * 2 + ri) * 512 + ot * 32 + oth];
        BT[(ri * 64 + i) * 33 + oth] = bf16_split_pack(v);
    }
    __syncthreads();
    int wv = t >> 6, lane = t & 63, quad = lane >> 4, l15 = lane & 15;
    int nt = wv & 1, mtp = wv >> 1;
    f32x4 aR[2], aI[2];
    aR[0]=(f32x4){0.f,0.f,0.f,0.f}; aR[1]=aR[0]; aI[0]=aR[0]; aI[1]=aR[0];
    #pragma unroll
    for (int kc = 0; kc < 2; ++kc) {
        short8 Brh, Brl, Bih, Bil;
        #pragma unroll
        for (int j = 0; j < 8; ++j) {
            int i = kc * 32 + quad * 8 + j;
            unsigned int br = BT[i * 33 + nt * 16 + l15];
            unsigned int bi = BT[(64 + i) * 33 + nt * 16 + l15];
            Brh[j] = (short)(br & 0xffffu); Brl[j] = (short)(br >> 16);
            Bih[j] = (short)(bi & 0xffffu); Bil[j] = (short)(bi >> 16);
        }
        #pragma unroll
        for (int mi = 0; mi < 2; ++mi) {
            int mt = mtp * 2 + mi;
            const short8* ap = (const short8*)(Am + ((size_t)(((m * 4 + mt) * 2 + kc) * 64 + lane)) * 48);
            short8 Arh = ap[0], Arl = ap[1], Aih = ap[2], Ail = ap[3], Anh = ap[4], Anl = ap[5];
            aR[mi] = MFMA16(Arh, Brh, aR[mi]);
            aR[mi] = MFMA16(Arl, Brh, aR[mi]);
            aR[mi] = MFMA16(Arh, Brl, aR[mi]);
            aR[mi] = MFMA16(Anh, Bih, aR[mi]);
            aR[mi] = MFMA16(Anl, Bih, aR[mi]);
            aR[mi] = MFMA16(Anh, Bil, aR[mi]);
            aI[mi] = MFMA16(Arh, Bih, aI[mi]);
            aI[mi] = MFMA16(Arl, Bih, aI[mi]);
            aI[mi] = MFMA16(Arh, Bil, aI[mi]);
            aI[mi] = MFMA16(Aih, Brh, aI[mi]);
            aI[mi] = MFMA16(Ail, Brh, aI[mi]);
            aI[mi] = MFMA16(Aih, Brl, aI[mi]);
        }
    }
    int oth = ot * 32 + nt * 16 + l15;
    #pragma unroll
    for (int mi = 0; mi < 2; ++mi) {
        int o = (mtp * 2 + mi) * 16 + quad * 4;
        #pragma unroll
        for (int r = 0; r < 4; ++r) {
            uint2 v;
            v.x = bf16_split_pack(aR[mi][r]);
            v.y = bf16_split_pack(aI[mi][r]);
            *(uint2*)(Vm + ((size_t)(o + r) * 512 + oth) * 32 + m * 2) = v;
        }
    }
}

// ---------------------------------------------------------------------------
// Fused inverse DFT (both axes) -> s as PLAIN BF16 (2 B).
// grid(8 yt, 8 wt, 64 p).
// ---------------------------------------------------------------------------
__global__ __launch_bounds__(256) void k_inv(const unsigned int* __restrict__ VmW, const unsigned int* __restrict__ VmH,
                                             const short* __restrict__ GbF, unsigned short* __restrict__ s) {
    int t = threadIdx.x;
    int yt = blockIdx.x, wt = blockIdx.y, p = blockIdx.z;
    int wv = t >> 6, lane = t & 63, quad = lane >> 4, l15 = lane & 15;
    int ys = yt * 64 + wv * 16;
    const uint4* a2p = (const uint4*)(VmW + ((size_t)p * 512 + ys + l15) * 32 + quad * 8);
    unsigned int aw[8];
    {
        uint4 x0 = a2p[0], x1 = a2p[1];
        aw[0]=x0.x; aw[1]=x0.y; aw[2]=x0.z; aw[3]=x0.w;
        aw[4]=x1.x; aw[5]=x1.y; aw[6]=x1.z; aw[7]=x1.w;
    }
    short8 A2h, A2l; unzip8(aw, A2h, A2l);
    const short8* g1 = (const short8*)(GbF + (((yt * 4 + wv) * 64 + lane) << 4));
    short8 A1h = g1[0], A1l = g1[1];
    #pragma unroll
    for (int nt = 0; nt < 4; ++nt) {
        int wb = wt * 64 + nt * 16;
        const uint4* b1p = (const uint4*)(VmH + ((size_t)p * 512 + wb + l15) * 32 + quad * 8);
        unsigned int bw[8];
        uint4 x0 = b1p[0], x1 = b1p[1];
        bw[0]=x0.x; bw[1]=x0.y; bw[2]=x0.z; bw[3]=x0.w;
        bw[4]=x1.x; bw[5]=x1.y; bw[6]=x1.z; bw[7]=x1.w;
        short8 B1h, B1l; unzip8(bw, B1h, B1l);
        const short8* g2 = (const short8*)(GbF + (((wt * 4 + nt) * 64 + lane) << 4));
        short8 B2h = g2[0], B2l = g2[1];
        f32x4 acc = (f32x4){0.f,0.f,0.f,0.f};
        acc = MFMA16(A1h, B1h, acc);
        acc = MFMA16(A1l, B1h, acc);
        acc = MFMA16(A1h, B1l, acc);
        acc = MFMA16(A2h, B2h, acc);
        acc = MFMA16(A2l, B2h, acc);
        acc = MFMA16(A2h, B2l, acc);
        #pragma unroll
        for (int r = 0; r < 4; ++r)
            s[((size_t)p * 512 + ys + quad * 4 + r) * 512 + wb + l15] = bf16_rne(acc[r]);
    }
}

// ---------------------------------------------------------------------------
// MFMA FFN, 128-PIXEL tile (grid 2048): h(bf16) += gelu(W2.gelu(W1.s+b1)+b2).
// 128 px x 2 B = 256 B per channel row = one FULL HBM sector written by 16
// lanes of one wave in one instruction -> no partial-sector write
// amplification (R13/R14: 65 MB written for 32 logical; XCD swizzle did NOT
// fix it -> fix it within-wave instead).
// Waves: wv handles n-slices {wv*32+0..15, wv*32+16..31}; acc[2][4].
// sB/tB stride-33 (proven); oT is BF16 stride-136 u16 (16-B-aligned uint4
// reads), aliases sB. LDS 34304 B -> 4 blocks/CU.
// last==1: fused decoder to d_out.
// ---------------------------------------------------------------------------
union FfnSmem {
    unsigned int  sB[128 * 33];     // 16896 B, staged bf16 s tile [pix][ch-pair]
    unsigned short oTb[64 * 136];   // 17408 B, epilogue2 bf16 transpose tile
};

__global__ __launch_bounds__(256, 4) void k_ffn2m(const unsigned short* __restrict__ in, unsigned short* __restrict__ out,
                                                  const short* __restrict__ w1f, const float* __restrict__ b1v,
                                                  const short* __restrict__ w2f, const float* __restrict__ b2v,
                                                  const float* __restrict__ Wd, const float* __restrict__ bd,
                                                  float* __restrict__ dout, int last) {
    __shared__ __align__(16) FfnSmem u;
    __shared__ __align__(16) unsigned int tB[128 * 33];
    int t = threadIdx.x;
    int pixBase = blockIdx.x * 128;
    int lane15 = t & 15;
    int quad   = (t >> 4) & 3;
    int wv     = t >> 6;
    int k  = t >> 3;                           // staging channel pair 0..31
    int po = t & 7;                            // staging pixel oct (first half)
    int oct = t & 15;                          // store pixel oct 0..15
    int cg  = t >> 4;                          // store channel group 0..15

    // ---- independent loads up front: h residual prefetch + s tile ----
    uint4 hr[4];
    #pragma unroll
    for (int j = 0; j < 4; ++j) {
        int c = cg + 16 * j;
        hr[j] = *(const uint4*)(out + (size_t)c * NPIX + pixBase + oct * 8);
    }
    #pragma unroll
    for (int half = 0; half < 2; ++half) {
        int so = (po + half * 8) * 8;          // pixel base 0..120
        uint4 a = *(const uint4*)(in + (size_t)(2 * k) * NPIX + pixBase + so);
        uint4 b = *(const uint4*)(in + (size_t)(2 * k + 1) * NPIX + pixBase + so);
        unsigned int aw[4] = {a.x, a.y, a.z, a.w};
        unsigned int bw[4] = {b.x, b.y, b.z, b.w};
        #pragma unroll
        for (int i = 0; i < 4; ++i) {
            int pix = so + 2 * i;
            u.sB[pix * 33 + k]       = (aw[i] & 0xffffu) | (bw[i] << 16);
            u.sB[(pix + 1) * 33 + k] = (aw[i] >> 16) | (bw[i] & 0xffff0000u);
        }
    }

    short8 W1h[8], W1l[8];
    #pragma unroll
    for (int s8 = 0; s8 < 8; ++s8) {
        const short8* p = (const short8*)(w1f + (((size_t)s8 * 64 + (t & 63)) << 4));
        W1h[s8] = p[0]; W1l[s8] = p[1];
    }

    f32x4 acc[2][4];
    #pragma unroll
    for (int ns = 0; ns < 2; ++ns)
        #pragma unroll
        for (int mt = 0; mt < 4; ++mt) acc[ns][mt] = (f32x4){0.f, 0.f, 0.f, 0.f};

    __syncthreads();

    // ---- GEMM1: 2-term, 2 n-slices ----
    #pragma unroll
    for (int ns = 0; ns < 2; ++ns) {
        int row = wv * 32 + ns * 16 + lane15;
        #pragma unroll
        for (int kc = 0; kc < 2; ++kc) {
            union { unsigned int w[4]; short8 v; } bb;
            #pragma unroll
            for (int i = 0; i < 4; ++i)
                bb.w[i] = u.sB[row * 33 + kc * 16 + quad * 4 + i];
            #pragma unroll
            for (int mt = 0; mt < 4; ++mt) {
                int s8 = mt * 2 + kc;
                acc[ns][mt] = MFMA16(W1h[s8], bb.v, acc[ns][mt]);
                acc[ns][mt] = MFMA16(W1l[s8], bb.v, acc[ns][mt]);
            }
        }
    }

    // ---- epilogue1: gelu -> bf16 pairs -> tB ----
    #pragma unroll
    for (int ns = 0; ns < 2; ++ns) {
        int row = wv * 32 + ns * 16 + lane15;
        #pragma unroll
        for (int mt = 0; mt < 4; ++mt) {
            const float* bp = b1v + mt * 16 + quad * 4;
            float g[4];
            #pragma unroll
            for (int r = 0; r < 4; ++r) g[r] = gelu_f(acc[ns][mt][r] + bp[r]);
            int cp = (mt * 16 + quad * 4) >> 1;
            tB[row * 33 + cp]     = (unsigned int)bf16_rne(g[0]) | ((unsigned int)bf16_rne(g[1]) << 16);
            tB[row * 33 + cp + 1] = (unsigned int)bf16_rne(g[2]) | ((unsigned int)bf16_rne(g[3]) << 16);
            acc[ns][mt] = (f32x4){0.f, 0.f, 0.f, 0.f};
        }
    }

    short8 W2h[8], W2l[8];
    #pragma unroll
    for (int s8 = 0; s8 < 8; ++s8) {
        const short8* p = (const short8*)(w2f + (((size_t)s8 * 64 + (t & 63)) << 4));
        W2h[s8] = p[0]; W2l[s8] = p[1];
    }

    __syncthreads();   // tB visible; fences GEMM1 sB reads (oTb may alias)

    // ---- GEMM2: 2-term, 2 n-slices ----
    #pragma unroll
    for (int ns = 0; ns < 2; ++ns) {
        int row = wv * 32 + ns * 16 + lane15;
        #pragma unroll
        for (int kc = 0; kc < 2; ++kc) {
            union { unsigned int w[4]; short8 v; } bb;
            #pragma unroll
            for (int i = 0; i < 4; ++i)
                bb.w[i] = tB[row * 33 + kc * 16 + quad * 4 + i];
            #pragma unroll
            for (int mt = 0; mt < 4; ++mt) {
                int s8 = mt * 2 + kc;
                acc[ns][mt] = MFMA16(W2h[s8], bb.v, acc[ns][mt]);
                acc[ns][mt] = MFMA16(W2l[s8], bb.v, acc[ns][mt]);
            }
        }
    }

    // ---- epilogue2: gelu -> bf16 oTb (aliases sB) ----
    #pragma unroll
    for (int ns = 0; ns < 2; ++ns) {
        int px = wv * 32 + ns * 16 + lane15;
        #pragma unroll
        for (int mt = 0; mt < 4; ++mt) {
            const float* bp = b2v + mt * 16 + quad * 4;
            #pragma unroll
            for (int r = 0; r < 4; ++r) {
                int c = mt * 16 + quad * 4 + r;
                u.oTb[c * 136 + px] = bf16_rne(gelu_f(acc[ns][mt][r] + bp[r]));
            }
        }
    }
    __syncthreads();

    if (!last) {
        // ---- h(bf16) += increment: (c,oct) units, uint4, full 256-B sectors/wave ----
        #pragma unroll
        for (int j = 0; j < 4; ++j) {
            int c = cg + 16 * j;
            uint4 gv = *(const uint4*)&u.oTb[c * 136 + oct * 8];
            unsigned int hw[4] = {hr[j].x, hr[j].y, hr[j].z, hr[j].w};
            unsigned int gw[4] = {gv.x, gv.y, gv.z, gv.w};
            uint4 o;
            unsigned int* op = &o.x;
            #pragma unroll
            for (int i = 0; i < 4; ++i) {
                float f0 = bf16_tof((unsigned short)(hw[i] & 0xffffu)) + bf16_tof((unsigned short)(gw[i] & 0xffffu));
                float f1 = bf16_tof((unsigned short)(hw[i] >> 16))     + bf16_tof((unsigned short)(gw[i] >> 16));
                op[i] = (unsigned int)bf16_rne(f0) | ((unsigned int)bf16_rne(f1) << 16);
            }
            *(uint4*)(out + (size_t)c * NPIX + pixBase + oct * 8) = o;
        }
    } else {
        // ---- fused decoder: dout = sum_c Wd[c]*(hres+gv) + bd (red aliases tB) ----
        float part[8] = {0.f,0.f,0.f,0.f,0.f,0.f,0.f,0.f};
        #pragma unroll
        for (int j = 0; j < 4; ++j) {
            int c = cg + 16 * j;
            float wd = Wd[c];
            uint4 gv = *(const uint4*)&u.oTb[c * 136 + oct * 8];
            unsigned int hw[4] = {hr[j].x, hr[j].y, hr[j].z, hr[j].w};
            unsigned int gw[4] = {gv.x, gv.y, gv.z, gv.w};
            #pragma unroll
            for (int i = 0; i < 4; ++i) {
                part[2*i]   += wd * (bf16_tof((unsigned short)(hw[i] & 0xffffu)) + bf16_tof((unsigned short)(gw[i] & 0xffffu)));
                part[2*i+1] += wd * (bf16_tof((unsigned short)(hw[i] >> 16))     + bf16_tof((unsigned short)(gw[i] >> 16)));
            }
        }
        float* red = (float*)tB;               // 16 grp x 132 stride x 4 B = 8448 B fits tB
        #pragma unroll
        for (int i = 0; i < 8; ++i)
            red[cg * 132 + oct * 8 + i] = part[i];
        __syncthreads();
        if (t < 128) {
            float sum = bd[0];
            #pragma unroll
            for (int gg = 0; gg < 16; ++gg)
                sum += red[gg * 132 + t];
            dout[pixBase + t] = sum;
        }
    }
}

extern "C" void kernel_launch(void* const* d_in, const int* in_sizes, int n_in,
                              void* d_out, int out_size, void* d_ws, size_t ws_size,
                              hipStream_t stream) {
    (void)in_sizes; (void)n_in; (void)out_size; (void)ws_size;
    const float* u   = (const float*)d_in[0];
    const float* xc  = (const float*)d_in[1];
    const float* We  = (const float*)d_in[2];
    const float* be  = (const float*)d_in[3];
    const float* W1  = (const float*)d_in[4];
    const float* b1  = (const float*)d_in[5];
    const float* W2  = (const float*)d_in[6];
    const float* b2  = (const float*)d_in[7];
    const float* Are = (const float*)d_in[8];
    const float* Aim = (const float*)d_in[9];
    const float* Wd  = (const float*)d_in[10];
    const float* bd  = (const float*)d_in[11];

    // workspace layout, ~93 MB used
    char* ws = (char*)d_ws;
    unsigned short* h = (unsigned short*)ws;                  // 32 MB (bf16)
    unsigned short* s = (unsigned short*)(ws + (size_t)33554432); // 32 MB (bf16)
    float* VfH = (float*)(ws + (size_t)67108864);             // 4 MB: [64][32][512]
    float* VfW = VfH + (size_t)1048576;                       // 4 MB
    unsigned int* VmH = (unsigned int*)(VfW + 1048576);       // 4 MB split-packed
    unsigned int* VmW = VmH + (size_t)1048576;                // 4 MB
    short* FbB = (short*)(VmW + 1048576);                     // 64 KB
    short* GbF = FbB + 32768;                                 // 64 KB
    short* Am  = GbF + 32768;                                 // 6 MB
    short* Wpk = Am  + (size_t)65536 * 48;                    // 128 KB

    k_setup<<<1312, 256, 0, stream>>>(W1, W2, Are, Aim, u, xc, We, be,
                                      FbB, GbF, Wpk, Am, h);

    for (int l = 0; l < 4; ++l) {
        k_fwd<<<dim3(64, 8, 2), 256, 0, stream>>>(h, FbB, VfH, VfW);
        k_mix2<<<512, 256, 0, stream>>>(VfH, VfW, Am + (size_t)(l * 2) * ASLAB, VmH, VmW);
        k_inv<<<dim3(8, 8, 64), 256, 0, stream>>>(VmW, VmH, GbF, s);
        k_ffn2m<<<2048, 256, 0, stream>>>(s, h,
                                          Wpk + (size_t)(l * 2 + 0) * 8192, b1 + (size_t)l * 64,
                                          Wpk + (size_t)(l * 2 + 1) * 8192, b2 + (size_t)l * 64,
                                          Wd, bd, (float*)d_out, (l == 3) ? 1 : 0);
    }
}

// Round 2
// 424.976 us; speedup vs baseline: 1.1539x; 1.1539x over previous
//
#include <hip/hip_runtime.h>

#define NPIX (512*512)

typedef __attribute__((ext_vector_type(8))) short short8;   // 8 bf16 in 4 VGPRs
typedef __attribute__((ext_vector_type(4))) float f32x4;    // MFMA accumulator

#define MFMA16(A, B, C) __builtin_amdgcn_mfma_f32_16x16x32_bf16((A), (B), (C), 0, 0, 0)

// JAX gelu(approximate=True): x * sigmoid(2*sqrt(2/pi)*(x+0.044715x^3)); inf-safe.
__device__ __forceinline__ float gelu_f(float x) {
    return x / (1.0f + __expf(-1.5957691216057308f * (x + 0.044715f * x * x * x)));
}

// f32 -> bf16 bits (RNE)
__device__ __forceinline__ unsigned short bf16_rne(float x) {
    unsigned int b = __float_as_uint(x);
    unsigned int r = b + 0x7fffu + ((b >> 16) & 1u);
    return (unsigned short)(r >> 16);
}
__device__ __forceinline__ float bf16_tof(unsigned short h) {
    return __uint_as_float(((unsigned int)h) << 16);
}
__device__ __forceinline__ unsigned int bf16_split_pack(float x) {
    unsigned short hi = bf16_rne(x);
    unsigned short lo = bf16_rne(x - bf16_tof(hi));
    return (unsigned int)hi | ((unsigned int)lo << 16);
}
// unzip 8 split-packed u32 (hi|lo<<16 per elem) -> hi-short8 / lo-short8
__device__ __forceinline__ void unzip8(const unsigned int* w, short8& h, short8& l) {
    union { unsigned int u[4]; short8 v; } hh, ll;
    #pragma unroll
    for (int i = 0; i < 4; ++i) {
        hh.u[i] = (w[2*i] & 0xffffu) | (w[2*i+1] << 16);
        ll.u[i] = (w[2*i] >> 16) | (w[2*i+1] & 0xffff0000u);
    }
    h = hh.v; l = ll.v;
}

#define ASLAB ((size_t)16 * 4 * 2 * 64 * 48)   // shorts per (l,ax) in Am

// Vm u32 index: [p][y>>4][m][y&15][ri]  (R1: full-128B-line single-wave stores;
// was [p][y][m*2+ri] -> 8B per block per 64B sector scattered over 8 XCDs).
#define VM_IDX(p, yT, m, yL) (((((size_t)(p) * 32 + (yT)) * 16 + (m)) * 16 + (yL)) * 2)

// ---------------------------------------------------------------------------
// Merged setup + encoder: blocks 0..15 basis tables, 16..31 FFN weights,
// 32..287 spectral A-weights, 288..1311 encoder (h stored bf16).
// ---------------------------------------------------------------------------
__global__ __launch_bounds__(256) void k_setup(const float* __restrict__ W1, const float* __restrict__ W2,
                                               const float* __restrict__ Are, const float* __restrict__ Aim,
                                               const float* __restrict__ u, const float* __restrict__ xc,
                                               const float* __restrict__ We, const float* __restrict__ be,
                                               short* __restrict__ FbB, short* __restrict__ GbF,
                                               short* __restrict__ Wpk, short* __restrict__ Am,
                                               unsigned short* __restrict__ h) {
    int b = blockIdx.x;
    int t = threadIdx.x;
    if (b < 16) {
        int id = b * 256 + t;
        int lane = id & 63;
        int quad = lane >> 4, l15 = lane & 15;
        short* dst;
        int n0, nstep, o0, ostep;
        float wscale = 1.0f;
        if (id < 2048) {
            int nt = (id >> 6) & 1, kc = id >> 7;
            dst = FbB + id * 16;
            n0 = kc * 32 + quad * 8; nstep = 1;
            o0 = nt * 16 + l15;      ostep = 0;
        } else {
            int id2 = id - 2048;
            dst = GbF + id2 * 16;
            int tt = id2 >> 6;
            n0 = tt * 16 + l15;      nstep = 0;
            o0 = quad * 8;           ostep = 1;
            wscale = 1.0f / 512.0f;
        }
        #pragma unroll
        for (int j = 0; j < 8; ++j) {
            int n = n0 + nstep * j;
            int o = o0 + ostep * j;
            int m = o >> 1, ri = o & 1;
            int k = (n * m) & 511;
            float sv, cv;
            sincosf(6.283185307179586f * (1.0f / 512.0f) * (float)k, &sv, &cv);
            float v = ri ? -sv : cv;
            if (id >= 2048) v *= (m == 0 ? 1.0f : 2.0f) * wscale;
            unsigned short hi = bf16_rne(v);
            dst[j]     = (short)hi;
            dst[8 + j] = (short)bf16_rne(v - bf16_tof(hi));
        }
    } else if (b < 32) {
        int tid = (b - 16) * 256 + t;
        int lane = tid & 63;
        int kc = (tid >> 6) & 1;
        int mt = (tid >> 7) & 3;
        int wg = tid >> 9;
        int layer = wg >> 1, which = wg & 1;
        const float* Wsrc = (which ? W2 : W1) + (size_t)layer * 4096;
        int o  = mt * 16 + (lane & 15);
        int c0 = kc * 32 + ((lane >> 4) & 3) * 8;
        short* dst = Wpk + (size_t)tid * 16;
        #pragma unroll
        for (int j = 0; j < 8; ++j) {
            float x = Wsrc[o * 64 + c0 + j];
            unsigned short hi = bf16_rne(x);
            dst[j]     = (short)hi;
            dst[8 + j] = (short)bf16_rne(x - bf16_tof(hi));
        }
    } else if (b < 288) {
        int id = (b - 32) * 256 + t;
        int lane = id & 63;
        int kc  = (id >> 6) & 1;
        int mt  = (id >> 7) & 3;
        int m   = (id >> 9) & 15;
        int lax = id >> 13;
        int l = lax >> 1, ax = lax & 1;
        int o  = mt * 16 + (lane & 15);
        int i0 = kc * 32 + ((lane >> 4) & 3) * 8;
        short* dst = Am + (size_t)id * 48;
        #pragma unroll
        for (int j = 0; j < 8; ++j) {
            size_t src = (((size_t)(l * 64 + o) * 64 + (i0 + j)) * 16 + m) * 2 + ax;
            float ar = Are[src], ai = Aim[src];
            unsigned short hh;
            hh = bf16_rne(ar);  dst[j]      = (short)hh; dst[8 + j]  = (short)bf16_rne(ar - bf16_tof(hh));
            hh = bf16_rne(ai);  dst[16 + j] = (short)hh; dst[24 + j] = (short)bf16_rne(ai - bf16_tof(hh));
            hh = bf16_rne(-ai); dst[32 + j] = (short)hh; dst[40 + j] = (short)bf16_rne(-ai - bf16_tof(hh));
        }
    } else {
        // encoder: h[p][pix] = bf16(We.x + be)
        int pix = (b - 288) * 256 + t;
        float x0 = xc[pix], x1 = xc[NPIX + pix], uu = u[pix];
        #pragma unroll 8
        for (int p = 0; p < 64; ++p) {
            float v = We[p * 3] * x0 + We[p * 3 + 1] * x1 + We[p * 3 + 2] * uu + be[p];
            h[(size_t)p * NPIX + pix] = bf16_rne(v);
        }
    }
}

// ---------------------------------------------------------------------------
// Merged forward DFT, both axes, h in bf16 (B-frag direct reinterpret; A-side
// basis split -> 2-term MFMA). grid(64 p, 8 ntile, 2 axis).
// ---------------------------------------------------------------------------
__global__ __launch_bounds__(256) void k_fwd(const unsigned short* __restrict__ h, const short* __restrict__ FbB,
                                             float* __restrict__ VfH, float* __restrict__ VfW) {
    int t = threadIdx.x;
    int p = blockIdx.x, ntb = blockIdx.y, axis = blockIdx.z;
    int wv = t >> 6, lane = t & 63, quad = lane >> 4, l15 = lane & 15;
    int n = ntb * 64 + wv * 16 + l15;
    f32x4 acc[2];
    acc[0] = (f32x4){0.f,0.f,0.f,0.f}; acc[1] = (f32x4){0.f,0.f,0.f,0.f};
    #pragma unroll 4
    for (int kc = 0; kc < 16; ++kc) {
        int kb = kc * 32 + quad * 8;
        short8 Bv;
        if (axis == 0) {
            const unsigned short* hp = h + ((size_t)p * 512 + kb) * 512 + n;
            #pragma unroll
            for (int j = 0; j < 8; ++j) Bv[j] = (short)hp[(size_t)j * 512];
        } else {
            const unsigned short* hp = h + ((size_t)p * 512 + n) * 512 + kb;
            Bv = *(const short8*)hp;
        }
        #pragma unroll
        for (int mt = 0; mt < 2; ++mt) {
            const short8* ap = (const short8*)(FbB + (((kc * 2 + mt) * 64 + lane) << 4));
            short8 Ah = ap[0], Al = ap[1];
            acc[mt] = MFMA16(Ah, Bv, acc[mt]);
            acc[mt] = MFMA16(Al, Bv, acc[mt]);
        }
    }
    float* vp = (axis ? VfW : VfH) + (size_t)p * 32 * 512;
    #pragma unroll
    for (int mt = 0; mt < 2; ++mt)
        #pragma unroll
        for (int r = 0; r < 4; ++r)
            vp[(size_t)(mt * 16 + quad * 4 + r) * 512 + n] = acc[mt][r];
}

// ---------------------------------------------------------------------------
// Merged mode mixing, both axes. Epilogue writes Vm SPLIT-PACKED u32 in the
// [p][y>>4][m][y&15][ri] layout: one 128-B contiguous line per (o,r) store.
// grid 512 (axis = bid>>8; m = bid&15, otile = (bid>>4)&15), block 256.
// ---------------------------------------------------------------------------
__global__ __launch_bounds__(256) void k_mix2(const float* __restrict__ VfH, const float* __restrict__ VfW,
                                              const short* __restrict__ AmL,
                                              unsigned int* __restrict__ VmH, unsigned int* __restrict__ VmW) {
    __shared__ unsigned int BT[2 * 64 * 33];
    int bid = blockIdx.x;
    int axis = bid >> 8;
    int m  = bid & 15;
    int ot = (bid >> 4) & 15;
    const float* Vf = axis ? VfW : VfH;
    unsigned int* Vm = axis ? VmW : VmH;
    const short* Am = AmL + (size_t)axis * ASLAB;
    int t = threadIdx.x;
    #pragma unroll
    for (int it = 0; it < 16; ++it) {
        int idx = it * 256 + t;
        int oth = idx & 31, ri = (idx >> 5) & 1, i = idx >> 6;
        float v = Vf[((size_t)i * 32 + m * 2 + ri) * 512 + ot * 32 + oth];
        BT[(ri * 64 + i) * 33 + oth] = bf16_split_pack(v);
    }
    __syncthreads();
    int wv = t >> 6, lane = t & 63, quad = lane >> 4, l15 = lane & 15;
    int nt = wv & 1, mtp = wv >> 1;
    f32x4 aR[2], aI[2];
    aR[0]=(f32x4){0.f,0.f,0.f,0.f}; aR[1]=aR[0]; aI[0]=aR[0]; aI[1]=aR[0];
    #pragma unroll
    for (int kc = 0; kc < 2; ++kc) {
        short8 Brh, Brl, Bih, Bil;
        #pragma unroll
        for (int j = 0; j < 8; ++j) {
            int i = kc * 32 + quad * 8 + j;
            unsigned int br = BT[i * 33 + nt * 16 + l15];
            unsigned int bi = BT[(64 + i) * 33 + nt * 16 + l15];
            Brh[j] = (short)(br & 0xffffu); Brl[j] = (short)(br >> 16);
            Bih[j] = (short)(bi & 0xffffu); Bil[j] = (short)(bi >> 16);
        }
        #pragma unroll
        for (int mi = 0; mi < 2; ++mi) {
            int mt = mtp * 2 + mi;
            const short8* ap = (const short8*)(Am + ((size_t)(((m * 4 + mt) * 2 + kc) * 64 + lane)) * 48);
            short8 Arh = ap[0], Arl = ap[1], Aih = ap[2], Ail = ap[3], Anh = ap[4], Anl = ap[5];
            aR[mi] = MFMA16(Arh, Brh, aR[mi]);
            aR[mi] = MFMA16(Arl, Brh, aR[mi]);
            aR[mi] = MFMA16(Arh, Brl, aR[mi]);
            aR[mi] = MFMA16(Anh, Bih, aR[mi]);
            aR[mi] = MFMA16(Anl, Bih, aR[mi]);
            aR[mi] = MFMA16(Anh, Bil, aR[mi]);
            aI[mi] = MFMA16(Arh, Bih, aI[mi]);
            aI[mi] = MFMA16(Arl, Bih, aI[mi]);
            aI[mi] = MFMA16(Arh, Bil, aI[mi]);
            aI[mi] = MFMA16(Aih, Brh, aI[mi]);
            aI[mi] = MFMA16(Ail, Brh, aI[mi]);
            aI[mi] = MFMA16(Aih, Brl, aI[mi]);
        }
    }
    // R1 layout: y = ot*32 + nt*16 + l15 -> yT = ot*2+nt (wave-uniform), yL = l15.
    // Each (o,r) store: 16 lanes x 8 B = one aligned 128-B line, single wave.
    int yT = ot * 2 + nt;
    #pragma unroll
    for (int mi = 0; mi < 2; ++mi) {
        int o = (mtp * 2 + mi) * 16 + quad * 4;
        #pragma unroll
        for (int r = 0; r < 4; ++r) {
            uint2 v;
            v.x = bf16_split_pack(aR[mi][r]);
            v.y = bf16_split_pack(aI[mi][r]);
            *(uint2*)(Vm + VM_IDX(o + r, yT, m, l15)) = v;
        }
    }
}

// ---------------------------------------------------------------------------
// Fused inverse DFT (both axes) -> s as PLAIN BF16 (2 B).
// grid(8 yt, 8 wt, 64 p). Vm reads adapted to [p][y>>4][m][y&15][ri] layout:
// 4x uint2 per fragment, each instr a fully-coalesced 128-B line.
// ---------------------------------------------------------------------------
__global__ __launch_bounds__(256) void k_inv(const unsigned int* __restrict__ VmW, const unsigned int* __restrict__ VmH,
                                             const short* __restrict__ GbF, unsigned short* __restrict__ s) {
    int t = threadIdx.x;
    int yt = blockIdx.x, wt = blockIdx.y, p = blockIdx.z;
    int wv = t >> 6, lane = t & 63, quad = lane >> 4, l15 = lane & 15;
    int ys = yt * 64 + wv * 16;
    int yT = yt * 4 + wv;                    // (ys+l15)>>4, wave-uniform
    unsigned int aw[8];
    #pragma unroll
    for (int tt = 0; tt < 4; ++tt) {
        uint2 q = *(const uint2*)(VmW + VM_IDX(p, yT, quad * 4 + tt, l15));
        aw[2*tt] = q.x; aw[2*tt+1] = q.y;
    }
    short8 A2h, A2l; unzip8(aw, A2h, A2l);
    const short8* g1 = (const short8*)(GbF + (((yt * 4 + wv) * 64 + lane) << 4));
    short8 A1h = g1[0], A1l = g1[1];
    #pragma unroll
    for (int nt = 0; nt < 4; ++nt) {
        int wb = wt * 64 + nt * 16;
        int wT = wt * 4 + nt;                // (wb+l15)>>4, wave-uniform
        unsigned int bw[8];
        #pragma unroll
        for (int tt = 0; tt < 4; ++tt) {
            uint2 q = *(const uint2*)(VmH + VM_IDX(p, wT, quad * 4 + tt, l15));
            bw[2*tt] = q.x; bw[2*tt+1] = q.y;
        }
        short8 B1h, B1l; unzip8(bw, B1h, B1l);
        const short8* g2 = (const short8*)(GbF + (((wt * 4 + nt) * 64 + lane) << 4));
        short8 B2h = g2[0], B2l = g2[1];
        f32x4 acc = (f32x4){0.f,0.f,0.f,0.f};
        acc = MFMA16(A1h, B1h, acc);
        acc = MFMA16(A1l, B1h, acc);
        acc = MFMA16(A1h, B1l, acc);
        acc = MFMA16(A2h, B2h, acc);
        acc = MFMA16(A2l, B2h, acc);
        acc = MFMA16(A2h, B2l, acc);
        #pragma unroll
        for (int r = 0; r < 4; ++r)
            s[((size_t)p * 512 + ys + quad * 4 + r) * 512 + wb + l15] = bf16_rne(acc[r]);
    }
}

// ---------------------------------------------------------------------------
// MFMA FFN, 128-PIXEL tile (grid 2048): h(bf16) += gelu(W2.gelu(W1.s+b1)+b2).
// 128 px x 2 B = 256 B per channel row = one FULL HBM sector written by 16
// lanes of one wave in one instruction -> no partial-sector write
// amplification (R13/R14: 65 MB written for 32 logical; XCD swizzle did NOT
// fix it -> fix it within-wave instead).
// Waves: wv handles n-slices {wv*32+0..15, wv*32+16..31}; acc[2][4].
// sB/tB stride-33 (proven); oT is BF16 stride-136 u16 (16-B-aligned uint4
// reads), aliases sB. LDS 34304 B -> 4 blocks/CU.
// last==1: fused decoder to d_out.
// ---------------------------------------------------------------------------
union FfnSmem {
    unsigned int  sB[128 * 33];     // 16896 B, staged bf16 s tile [pix][ch-pair]
    unsigned short oTb[64 * 136];   // 17408 B, epilogue2 bf16 transpose tile
};

__global__ __launch_bounds__(256, 4) void k_ffn2m(const unsigned short* __restrict__ in, unsigned short* __restrict__ out,
                                                  const short* __restrict__ w1f, const float* __restrict__ b1v,
                                                  const short* __restrict__ w2f, const float* __restrict__ b2v,
                                                  const float* __restrict__ Wd, const float* __restrict__ bd,
                                                  float* __restrict__ dout, int last) {
    __shared__ __align__(16) FfnSmem u;
    __shared__ __align__(16) unsigned int tB[128 * 33];
    int t = threadIdx.x;
    int pixBase = blockIdx.x * 128;
    int lane15 = t & 15;
    int quad   = (t >> 4) & 3;
    int wv     = t >> 6;
    int k  = t >> 3;                           // staging channel pair 0..31
    int po = t & 7;                            // staging pixel oct (first half)
    int oct = t & 15;                          // store pixel oct 0..15
    int cg  = t >> 4;                          // store channel group 0..15

    // ---- independent loads up front: h residual prefetch + s tile ----
    uint4 hr[4];
    #pragma unroll
    for (int j = 0; j < 4; ++j) {
        int c = cg + 16 * j;
        hr[j] = *(const uint4*)(out + (size_t)c * NPIX + pixBase + oct * 8);
    }
    #pragma unroll
    for (int half = 0; half < 2; ++half) {
        int so = (po + half * 8) * 8;          // pixel base 0..120
        uint4 a = *(const uint4*)(in + (size_t)(2 * k) * NPIX + pixBase + so);
        uint4 b = *(const uint4*)(in + (size_t)(2 * k + 1) * NPIX + pixBase + so);
        unsigned int aw[4] = {a.x, a.y, a.z, a.w};
        unsigned int bw[4] = {b.x, b.y, b.z, b.w};
        #pragma unroll
        for (int i = 0; i < 4; ++i) {
            int pix = so + 2 * i;
            u.sB[pix * 33 + k]       = (aw[i] & 0xffffu) | (bw[i] << 16);
            u.sB[(pix + 1) * 33 + k] = (aw[i] >> 16) | (bw[i] & 0xffff0000u);
        }
    }

    short8 W1h[8], W1l[8];
    #pragma unroll
    for (int s8 = 0; s8 < 8; ++s8) {
        const short8* p = (const short8*)(w1f + (((size_t)s8 * 64 + (t & 63)) << 4));
        W1h[s8] = p[0]; W1l[s8] = p[1];
    }

    f32x4 acc[2][4];
    #pragma unroll
    for (int ns = 0; ns < 2; ++ns)
        #pragma unroll
        for (int mt = 0; mt < 4; ++mt) acc[ns][mt] = (f32x4){0.f, 0.f, 0.f, 0.f};

    __syncthreads();

    // ---- GEMM1: 2-term, 2 n-slices ----
    #pragma unroll
    for (int ns = 0; ns < 2; ++ns) {
        int row = wv * 32 + ns * 16 + lane15;
        #pragma unroll
        for (int kc = 0; kc < 2; ++kc) {
            union { unsigned int w[4]; short8 v; } bb;
            #pragma unroll
            for (int i = 0; i < 4; ++i)
                bb.w[i] = u.sB[row * 33 + kc * 16 + quad * 4 + i];
            #pragma unroll
            for (int mt = 0; mt < 4; ++mt) {
                int s8 = mt * 2 + kc;
                acc[ns][mt] = MFMA16(W1h[s8], bb.v, acc[ns][mt]);
                acc[ns][mt] = MFMA16(W1l[s8], bb.v, acc[ns][mt]);
            }
        }
    }

    // ---- epilogue1: gelu -> bf16 pairs -> tB ----
    #pragma unroll
    for (int ns = 0; ns < 2; ++ns) {
        int row = wv * 32 + ns * 16 + lane15;
        #pragma unroll
        for (int mt = 0; mt < 4; ++mt) {
            const float* bp = b1v + mt * 16 + quad * 4;
            float g[4];
            #pragma unroll
            for (int r = 0; r < 4; ++r) g[r] = gelu_f(acc[ns][mt][r] + bp[r]);
            int cp = (mt * 16 + quad * 4) >> 1;
            tB[row * 33 + cp]     = (unsigned int)bf16_rne(g[0]) | ((unsigned int)bf16_rne(g[1]) << 16);
            tB[row * 33 + cp + 1] = (unsigned int)bf16_rne(g[2]) | ((unsigned int)bf16_rne(g[3]) << 16);
            acc[ns][mt] = (f32x4){0.f, 0.f, 0.f, 0.f};
        }
    }

    short8 W2h[8], W2l[8];
    #pragma unroll
    for (int s8 = 0; s8 < 8; ++s8) {
        const short8* p = (const short8*)(w2f + (((size_t)s8 * 64 + (t & 63)) << 4));
        W2h[s8] = p[0]; W2l[s8] = p[1];
    }

    __syncthreads();   // tB visible; fences GEMM1 sB reads (oTb may alias)

    // ---- GEMM2: 2-term, 2 n-slices ----
    #pragma unroll
    for (int ns = 0; ns < 2; ++ns) {
        int row = wv * 32 + ns * 16 + lane15;
        #pragma unroll
        for (int kc = 0; kc < 2; ++kc) {
            union { unsigned int w[4]; short8 v; } bb;
            #pragma unroll
            for (int i = 0; i < 4; ++i)
                bb.w[i] = tB[row * 33 + kc * 16 + quad * 4 + i];
            #pragma unroll
            for (int mt = 0; mt < 4; ++mt) {
                int s8 = mt * 2 + kc;
                acc[ns][mt] = MFMA16(W2h[s8], bb.v, acc[ns][mt]);
                acc[ns][mt] = MFMA16(W2l[s8], bb.v, acc[ns][mt]);
            }
        }
    }

    // ---- epilogue2: gelu -> bf16 oTb (aliases sB) ----
    #pragma unroll
    for (int ns = 0; ns < 2; ++ns) {
        int px = wv * 32 + ns * 16 + lane15;
        #pragma unroll
        for (int mt = 0; mt < 4; ++mt) {
            const float* bp = b2v + mt * 16 + quad * 4;
            #pragma unroll
            for (int r = 0; r < 4; ++r) {
                int c = mt * 16 + quad * 4 + r;
                u.oTb[c * 136 + px] = bf16_rne(gelu_f(acc[ns][mt][r] + bp[r]));
            }
        }
    }
    __syncthreads();

    if (!last) {
        // ---- h(bf16) += increment: (c,oct) units, uint4, full 256-B sectors/wave ----
        #pragma unroll
        for (int j = 0; j < 4; ++j) {
            int c = cg + 16 * j;
            uint4 gv = *(const uint4*)&u.oTb[c * 136 + oct * 8];
            unsigned int hw[4] = {hr[j].x, hr[j].y, hr[j].z, hr[j].w};
            unsigned int gw[4] = {gv.x, gv.y, gv.z, gv.w};
            uint4 o;
            unsigned int* op = &o.x;
            #pragma unroll
            for (int i = 0; i < 4; ++i) {
                float f0 = bf16_tof((unsigned short)(hw[i] & 0xffffu)) + bf16_tof((unsigned short)(gw[i] & 0xffffu));
                float f1 = bf16_tof((unsigned short)(hw[i] >> 16))     + bf16_tof((unsigned short)(gw[i] >> 16));
                op[i] = (unsigned int)bf16_rne(f0) | ((unsigned int)bf16_rne(f1) << 16);
            }
            *(uint4*)(out + (size_t)c * NPIX + pixBase + oct * 8) = o;
        }
    } else {
        // ---- fused decoder: dout = sum_c Wd[c]*(hres+gv) + bd (red aliases tB) ----
        float part[8] = {0.f,0.f,0.f,0.f,0.f,0.f,0.f,0.f};
        #pragma unroll
        for (int j = 0; j < 4; ++j) {
            int c = cg + 16 * j;
            float wd = Wd[c];
            uint4 gv = *(const uint4*)&u.oTb[c * 136 + oct * 8];
            unsigned int hw[4] = {hr[j].x, hr[j].y, hr[j].z, hr[j].w};
            unsigned int gw[4] = {gv.x, gv.y, gv.z, gv.w};
            #pragma unroll
            for (int i = 0; i < 4; ++i) {
                part[2*i]   += wd * (bf16_tof((unsigned short)(hw[i] & 0xffffu)) + bf16_tof((unsigned short)(gw[i] & 0xffffu)));
                part[2*i+1] += wd * (bf16_tof((unsigned short)(hw[i] >> 16))     + bf16_tof((unsigned short)(gw[i] >> 16)));
            }
        }
        float* red = (float*)tB;               // 16 grp x 132 stride x 4 B = 8448 B fits tB
        #pragma unroll
        for (int i = 0; i < 8; ++i)
            red[cg * 132 + oct * 8 + i] = part[i];
        __syncthreads();
        if (t < 128) {
            float sum = bd[0];
            #pragma unroll
            for (int gg = 0; gg < 16; ++gg)
                sum += red[gg * 132 + t];
            dout[pixBase + t] = sum;
        }
    }
}

extern "C" void kernel_launch(void* const* d_in, const int* in_sizes, int n_in,
                              void* d_out, int out_size, void* d_ws, size_t ws_size,
                              hipStream_t stream) {
    (void)in_sizes; (void)n_in; (void)out_size; (void)ws_size;
    const float* u   = (const float*)d_in[0];
    const float* xc  = (const float*)d_in[1];
    const float* We  = (const float*)d_in[2];
    const float* be  = (const float*)d_in[3];
    const float* W1  = (const float*)d_in[4];
    const float* b1  = (const float*)d_in[5];
    const float* W2  = (const float*)d_in[6];
    const float* b2  = (const float*)d_in[7];
    const float* Are = (const float*)d_in[8];
    const float* Aim = (const float*)d_in[9];
    const float* Wd  = (const float*)d_in[10];
    const float* bd  = (const float*)d_in[11];

    // workspace layout, ~93 MB used
    char* ws = (char*)d_ws;
    unsigned short* h = (unsigned short*)ws;                  // 32 MB (bf16)
    unsigned short* s = (unsigned short*)(ws + (size_t)33554432); // 32 MB (bf16)
    float* VfH = (float*)(ws + (size_t)67108864);             // 4 MB: [64][32][512]
    float* VfW = VfH + (size_t)1048576;                       // 4 MB
    unsigned int* VmH = (unsigned int*)(VfW + 1048576);       // 4 MB split-packed
    unsigned int* VmW = VmH + (size_t)1048576;                // 4 MB
    short* FbB = (short*)(VmW + 1048576);                     // 64 KB
    short* GbF = FbB + 32768;                                 // 64 KB
    short* Am  = GbF + 32768;                                 // 6 MB
    short* Wpk = Am  + (size_t)65536 * 48;                    // 128 KB

    k_setup<<<1312, 256, 0, stream>>>(W1, W2, Are, Aim, u, xc, We, be,
                                      FbB, GbF, Wpk, Am, h);

    for (int l = 0; l < 4; ++l) {
        k_fwd<<<dim3(64, 8, 2), 256, 0, stream>>>(h, FbB, VfH, VfW);
        k_mix2<<<512, 256, 0, stream>>>(VfH, VfW, Am + (size_t)(l * 2) * ASLAB, VmH, VmW);
        k_inv<<<dim3(8, 8, 64), 256, 0, stream>>>(VmW, VmH, GbF, s);
        k_ffn2m<<<2048, 256, 0, stream>>>(s, h,
                                          Wpk + (size_t)(l * 2 + 0) * 8192, b1 + (size_t)l * 64,
                                          Wpk + (size_t)(l * 2 + 1) * 8192, b2 + (size_t)l * 64,
                                          Wd, bd, (float*)d_out, (l == 3) ? 1 : 0);
    }
}

// Round 3
// 420.034 us; speedup vs baseline: 1.1675x; 1.0118x over previous
//
#include <hip/hip_runtime.h>

#define NPIX (512*512)

typedef __attribute__((ext_vector_type(8))) short short8;   // 8 bf16 in 4 VGPRs
typedef __attribute__((ext_vector_type(4))) float f32x4;    // MFMA accumulator

#define MFMA16(A, B, C) __builtin_amdgcn_mfma_f32_16x16x32_bf16((A), (B), (C), 0, 0, 0)

// JAX gelu(approximate=True): x * sigmoid(2*sqrt(2/pi)*(x+0.044715x^3)); inf-safe.
__device__ __forceinline__ float gelu_f(float x) {
    return x / (1.0f + __expf(-1.5957691216057308f * (x + 0.044715f * x * x * x)));
}

// f32 -> bf16 bits (RNE)
__device__ __forceinline__ unsigned short bf16_rne(float x) {
    unsigned int b = __float_as_uint(x);
    unsigned int r = b + 0x7fffu + ((b >> 16) & 1u);
    return (unsigned short)(r >> 16);
}
__device__ __forceinline__ float bf16_tof(unsigned short h) {
    return __uint_as_float(((unsigned int)h) << 16);
}
__device__ __forceinline__ unsigned int bf16_split_pack(float x) {
    unsigned short hi = bf16_rne(x);
    unsigned short lo = bf16_rne(x - bf16_tof(hi));
    return (unsigned int)hi | ((unsigned int)lo << 16);
}
// unzip 8 split-packed u32 (hi|lo<<16 per elem) -> hi-short8 / lo-short8
__device__ __forceinline__ void unzip8(const unsigned int* w, short8& h, short8& l) {
    union { unsigned int u[4]; short8 v; } hh, ll;
    #pragma unroll
    for (int i = 0; i < 4; ++i) {
        hh.u[i] = (w[2*i] & 0xffffu) | (w[2*i+1] << 16);
        ll.u[i] = (w[2*i] >> 16) | (w[2*i+1] & 0xffff0000u);
    }
    h = hh.v; l = ll.v;
}

#define ASLAB ((size_t)16 * 4 * 2 * 64 * 48)   // shorts per (l,ax) in Am

// Vm u32 index: [p][y>>4][m][y&15][ri]  (R1: full-128B-line single-wave stores;
// was [p][y][m*2+ri] -> 8B per block per 64B sector scattered over 8 XCDs).
#define VM_IDX(p, yT, m, yL) (((((size_t)(p) * 32 + (yT)) * 16 + (m)) * 16 + (yL)) * 2)

// ---------------------------------------------------------------------------
// Merged setup + encoder: blocks 0..15 basis tables, 16..31 FFN weights,
// 32..287 spectral A-weights, 288..1311 encoder (h stored bf16).
// ---------------------------------------------------------------------------
__global__ __launch_bounds__(256) void k_setup(const float* __restrict__ W1, const float* __restrict__ W2,
                                               const float* __restrict__ Are, const float* __restrict__ Aim,
                                               const float* __restrict__ u, const float* __restrict__ xc,
                                               const float* __restrict__ We, const float* __restrict__ be,
                                               short* __restrict__ FbB, short* __restrict__ GbF,
                                               short* __restrict__ Wpk, short* __restrict__ Am,
                                               unsigned short* __restrict__ h) {
    int b = blockIdx.x;
    int t = threadIdx.x;
    if (b < 16) {
        int id = b * 256 + t;
        int lane = id & 63;
        int quad = lane >> 4, l15 = lane & 15;
        short* dst;
        int n0, nstep, o0, ostep;
        float wscale = 1.0f;
        if (id < 2048) {
            int nt = (id >> 6) & 1, kc = id >> 7;
            dst = FbB + id * 16;
            n0 = kc * 32 + quad * 8; nstep = 1;
            o0 = nt * 16 + l15;      ostep = 0;
        } else {
            int id2 = id - 2048;
            dst = GbF + id2 * 16;
            int tt = id2 >> 6;
            n0 = tt * 16 + l15;      nstep = 0;
            o0 = quad * 8;           ostep = 1;
            wscale = 1.0f / 512.0f;
        }
        #pragma unroll
        for (int j = 0; j < 8; ++j) {
            int n = n0 + nstep * j;
            int o = o0 + ostep * j;
            int m = o >> 1, ri = o & 1;
            int k = (n * m) & 511;
            float sv, cv;
            sincosf(6.283185307179586f * (1.0f / 512.0f) * (float)k, &sv, &cv);
            float v = ri ? -sv : cv;
            if (id >= 2048) v *= (m == 0 ? 1.0f : 2.0f) * wscale;
            unsigned short hi = bf16_rne(v);
            dst[j]     = (short)hi;
            dst[8 + j] = (short)bf16_rne(v - bf16_tof(hi));
        }
    } else if (b < 32) {
        int tid = (b - 16) * 256 + t;
        int lane = tid & 63;
        int kc = (tid >> 6) & 1;
        int mt = (tid >> 7) & 3;
        int wg = tid >> 9;
        int layer = wg >> 1, which = wg & 1;
        const float* Wsrc = (which ? W2 : W1) + (size_t)layer * 4096;
        int o  = mt * 16 + (lane & 15);
        int c0 = kc * 32 + ((lane >> 4) & 3) * 8;
        short* dst = Wpk + (size_t)tid * 16;
        #pragma unroll
        for (int j = 0; j < 8; ++j) {
            float x = Wsrc[o * 64 + c0 + j];
            unsigned short hi = bf16_rne(x);
            dst[j]     = (short)hi;
            dst[8 + j] = (short)bf16_rne(x - bf16_tof(hi));
        }
    } else if (b < 288) {
        int id = (b - 32) * 256 + t;
        int lane = id & 63;
        int kc  = (id >> 6) & 1;
        int mt  = (id >> 7) & 3;
        int m   = (id >> 9) & 15;
        int lax = id >> 13;
        int l = lax >> 1, ax = lax & 1;
        int o  = mt * 16 + (lane & 15);
        int i0 = kc * 32 + ((lane >> 4) & 3) * 8;
        short* dst = Am + (size_t)id * 48;
        #pragma unroll
        for (int j = 0; j < 8; ++j) {
            size_t src = (((size_t)(l * 64 + o) * 64 + (i0 + j)) * 16 + m) * 2 + ax;
            float ar = Are[src], ai = Aim[src];
            unsigned short hh;
            hh = bf16_rne(ar);  dst[j]      = (short)hh; dst[8 + j]  = (short)bf16_rne(ar - bf16_tof(hh));
            hh = bf16_rne(ai);  dst[16 + j] = (short)hh; dst[24 + j] = (short)bf16_rne(ai - bf16_tof(hh));
            hh = bf16_rne(-ai); dst[32 + j] = (short)hh; dst[40 + j] = (short)bf16_rne(-ai - bf16_tof(hh));
        }
    } else {
        // encoder: h[p][pix] = bf16(We.x + be)
        int pix = (b - 288) * 256 + t;
        float x0 = xc[pix], x1 = xc[NPIX + pix], uu = u[pix];
        #pragma unroll 8
        for (int p = 0; p < 64; ++p) {
            float v = We[p * 3] * x0 + We[p * 3 + 1] * x1 + We[p * 3 + 2] * uu + be[p];
            h[(size_t)p * NPIX + pix] = bf16_rne(v);
        }
    }
}

// ---------------------------------------------------------------------------
// Merged forward DFT, both axes, h in bf16. grid(64 p, 8 ntile, 2 axis).
// axis1: direct short8 row reads (unchanged).
// axis0 (R2): coalesced uint4 tile loads + LDS transpose (stride-66 u16,
// packed k-pair u32 writes -> 2-way-free banks; dword fragment reads).
// Replaces 128 scalar global ushort gathers per wave.
// ---------------------------------------------------------------------------
__global__ __launch_bounds__(256) void k_fwd(const unsigned short* __restrict__ h, const short* __restrict__ FbB,
                                             float* __restrict__ VfH, float* __restrict__ VfW) {
    __shared__ unsigned short T[64 * 66];    // [n_local][k_local+pad], 8448 B
    int t = threadIdx.x;
    int p = blockIdx.x, ntb = blockIdx.y, axis = blockIdx.z;
    int wv = t >> 6, lane = t & 63, quad = lane >> 4, l15 = lane & 15;
    int n = ntb * 64 + wv * 16 + l15;
    int nL = wv * 16 + l15;
    f32x4 acc[2];
    acc[0] = (f32x4){0.f,0.f,0.f,0.f}; acc[1] = (f32x4){0.f,0.f,0.f,0.f};
    if (axis == 1) {
        #pragma unroll 4
        for (int kc = 0; kc < 16; ++kc) {
            int kb = kc * 32 + quad * 8;
            const unsigned short* hp = h + ((size_t)p * 512 + n) * 512 + kb;
            short8 Bv = *(const short8*)hp;
            #pragma unroll
            for (int mt = 0; mt < 2; ++mt) {
                const short8* ap = (const short8*)(FbB + (((kc * 2 + mt) * 64 + lane) << 4));
                short8 Ah = ap[0], Al = ap[1];
                acc[mt] = MFMA16(Ah, Bv, acc[mt]);
                acc[mt] = MFMA16(Al, Bv, acc[mt]);
            }
        }
    } else {
        int kp = t >> 3, c = t & 7;          // k-pair 0..31, n-oct 0..7
        for (int ch = 0; ch < 8; ++ch) {
            int k0 = ch * 64;
            // coalesced load: rows k0+2kp, k0+2kp+1; cols ntb*64 + c*8 .. +7
            const unsigned short* r0 = h + ((size_t)p * 512 + k0 + 2 * kp) * 512 + ntb * 64 + c * 8;
            uint4 a = *(const uint4*)r0;
            uint4 bq = *(const uint4*)(r0 + 512);
            unsigned int aw[4] = {a.x, a.y, a.z, a.w};
            unsigned int bw[4] = {bq.x, bq.y, bq.z, bq.w};
            __syncthreads();                  // previous chunk fully consumed
            #pragma unroll
            for (int i = 0; i < 4; ++i) {
                int n0 = c * 8 + 2 * i;
                // transposed k-pair packs: {h[k][n], h[k+1][n]}
                *(unsigned int*)&T[n0 * 66 + 2 * kp]       = (aw[i] & 0xffffu) | (bw[i] << 16);
                *(unsigned int*)&T[(n0 + 1) * 66 + 2 * kp] = (aw[i] >> 16) | (bw[i] & 0xffff0000u);
            }
            __syncthreads();
            #pragma unroll
            for (int kcl = 0; kcl < 2; ++kcl) {
                int kc = ch * 2 + kcl;
                union { unsigned int w[4]; short8 v; } bb;
                #pragma unroll
                for (int d = 0; d < 4; ++d)
                    bb.w[d] = *(const unsigned int*)&T[nL * 66 + kcl * 32 + quad * 8 + 2 * d];
                #pragma unroll
                for (int mt = 0; mt < 2; ++mt) {
                    const short8* ap = (const short8*)(FbB + (((kc * 2 + mt) * 64 + lane) << 4));
                    short8 Ah = ap[0], Al = ap[1];
                    acc[mt] = MFMA16(Ah, bb.v, acc[mt]);
                    acc[mt] = MFMA16(Al, bb.v, acc[mt]);
                }
            }
        }
    }
    float* vp = (axis ? VfW : VfH) + (size_t)p * 32 * 512;
    #pragma unroll
    for (int mt = 0; mt < 2; ++mt)
        #pragma unroll
        for (int r = 0; r < 4; ++r)
            vp[(size_t)(mt * 16 + quad * 4 + r) * 512 + n] = acc[mt][r];
}

// ---------------------------------------------------------------------------
// Merged mode mixing, both axes. Epilogue writes Vm SPLIT-PACKED u32 in the
// [p][y>>4][m][y&15][ri] layout: one 128-B contiguous line per (o,r) store.
// grid 512 (axis = bid>>8; m = bid&15, otile = (bid>>4)&15), block 256.
// ---------------------------------------------------------------------------
__global__ __launch_bounds__(256) void k_mix2(const float* __restrict__ VfH, const float* __restrict__ VfW,
                                              const short* __restrict__ AmL,
                                              unsigned int* __restrict__ VmH, unsigned int* __restrict__ VmW) {
    __shared__ unsigned int BT[2 * 64 * 33];
    int bid = blockIdx.x;
    int axis = bid >> 8;
    int m  = bid & 15;
    int ot = (bid >> 4) & 15;
    const float* Vf = axis ? VfW : VfH;
    unsigned int* Vm = axis ? VmW : VmH;
    const short* Am = AmL + (size_t)axis * ASLAB;
    int t = threadIdx.x;
    #pragma unroll
    for (int it = 0; it < 16; ++it) {
        int idx = it * 256 + t;
        int oth = idx & 31, ri = (idx >> 5) & 1, i = idx >> 6;
        float v = Vf[((size_t)i * 32 + m * 2 + ri) * 512 + ot * 32 + oth];
        BT[(ri * 64 + i) * 33 + oth] = bf16_split_pack(v);
    }
    __syncthreads();
    int wv = t >> 6, lane = t & 63, quad = lane >> 4, l15 = lane & 15;
    int nt = wv & 1, mtp = wv >> 1;
    f32x4 aR[2], aI[2];
    aR[0]=(f32x4){0.f,0.f,0.f,0.f}; aR[1]=aR[0]; aI[0]=aR[0]; aI[1]=aR[0];
    #pragma unroll
    for (int kc = 0; kc < 2; ++kc) {
        short8 Brh, Brl, Bih, Bil;
        #pragma unroll
        for (int j = 0; j < 8; ++j) {
            int i = kc * 32 + quad * 8 + j;
            unsigned int br = BT[i * 33 + nt * 16 + l15];
            unsigned int bi = BT[(64 + i) * 33 + nt * 16 + l15];
            Brh[j] = (short)(br & 0xffffu); Brl[j] = (short)(br >> 16);
            Bih[j] = (short)(bi & 0xffffu); Bil[j] = (short)(bi >> 16);
        }
        #pragma unroll
        for (int mi = 0; mi < 2; ++mi) {
            int mt = mtp * 2 + mi;
            const short8* ap = (const short8*)(Am + ((size_t)(((m * 4 + mt) * 2 + kc) * 64 + lane)) * 48);
            short8 Arh = ap[0], Arl = ap[1], Aih = ap[2], Ail = ap[3], Anh = ap[4], Anl = ap[5];
            aR[mi] = MFMA16(Arh, Brh, aR[mi]);
            aR[mi] = MFMA16(Arl, Brh, aR[mi]);
            aR[mi] = MFMA16(Arh, Brl, aR[mi]);
            aR[mi] = MFMA16(Anh, Bih, aR[mi]);
            aR[mi] = MFMA16(Anl, Bih, aR[mi]);
            aR[mi] = MFMA16(Anh, Bil, aR[mi]);
            aI[mi] = MFMA16(Arh, Bih, aI[mi]);
            aI[mi] = MFMA16(Arl, Bih, aI[mi]);
            aI[mi] = MFMA16(Arh, Bil, aI[mi]);
            aI[mi] = MFMA16(Aih, Brh, aI[mi]);
            aI[mi] = MFMA16(Ail, Brh, aI[mi]);
            aI[mi] = MFMA16(Aih, Brl, aI[mi]);
        }
    }
    // R1 layout: y = ot*32 + nt*16 + l15 -> yT = ot*2+nt (wave-uniform), yL = l15.
    // Each (o,r) store: 16 lanes x 8 B = one aligned 128-B line, single wave.
    int yT = ot * 2 + nt;
    #pragma unroll
    for (int mi = 0; mi < 2; ++mi) {
        int o = (mtp * 2 + mi) * 16 + quad * 4;
        #pragma unroll
        for (int r = 0; r < 4; ++r) {
            uint2 v;
            v.x = bf16_split_pack(aR[mi][r]);
            v.y = bf16_split_pack(aI[mi][r]);
            *(uint2*)(Vm + VM_IDX(o + r, yT, m, l15)) = v;
        }
    }
}

// ---------------------------------------------------------------------------
// Fused inverse DFT (both axes) -> s as PLAIN BF16 (2 B).
// grid(8 yt, 8 wt, 64 p). Vm reads in [p][y>>4][m][y&15][ri] layout:
// 4x uint2 per fragment, each instr a fully-coalesced 128-B line.
// ---------------------------------------------------------------------------
__global__ __launch_bounds__(256) void k_inv(const unsigned int* __restrict__ VmW, const unsigned int* __restrict__ VmH,
                                             const short* __restrict__ GbF, unsigned short* __restrict__ s) {
    int t = threadIdx.x;
    int yt = blockIdx.x, wt = blockIdx.y, p = blockIdx.z;
    int wv = t >> 6, lane = t & 63, quad = lane >> 4, l15 = lane & 15;
    int ys = yt * 64 + wv * 16;
    int yT = yt * 4 + wv;                    // (ys+l15)>>4, wave-uniform
    unsigned int aw[8];
    #pragma unroll
    for (int tt = 0; tt < 4; ++tt) {
        uint2 q = *(const uint2*)(VmW + VM_IDX(p, yT, quad * 4 + tt, l15));
        aw[2*tt] = q.x; aw[2*tt+1] = q.y;
    }
    short8 A2h, A2l; unzip8(aw, A2h, A2l);
    const short8* g1 = (const short8*)(GbF + (((yt * 4 + wv) * 64 + lane) << 4));
    short8 A1h = g1[0], A1l = g1[1];
    #pragma unroll
    for (int nt = 0; nt < 4; ++nt) {
        int wb = wt * 64 + nt * 16;
        int wT = wt * 4 + nt;                // (wb+l15)>>4, wave-uniform
        unsigned int bw[8];
        #pragma unroll
        for (int tt = 0; tt < 4; ++tt) {
            uint2 q = *(const uint2*)(VmH + VM_IDX(p, wT, quad * 4 + tt, l15));
            bw[2*tt] = q.x; bw[2*tt+1] = q.y;
        }
        short8 B1h, B1l; unzip8(bw, B1h, B1l);
        const short8* g2 = (const short8*)(GbF + (((wt * 4 + nt) * 64 + lane) << 4));
        short8 B2h = g2[0], B2l = g2[1];
        f32x4 acc = (f32x4){0.f,0.f,0.f,0.f};
        acc = MFMA16(A1h, B1h, acc);
        acc = MFMA16(A1l, B1h, acc);
        acc = MFMA16(A1h, B1l, acc);
        acc = MFMA16(A2h, B2h, acc);
        acc = MFMA16(A2l, B2h, acc);
        acc = MFMA16(A2h, B2l, acc);
        #pragma unroll
        for (int r = 0; r < 4; ++r)
            s[((size_t)p * 512 + ys + quad * 4 + r) * 512 + wb + l15] = bf16_rne(acc[r]);
    }
}

// ---------------------------------------------------------------------------
// MFMA FFN, 128-PIXEL tile (grid 2048): h(bf16) += gelu(W2.gelu(W1.s+b1)+b2).
// R2: weight fragments loaded AT USE (ns-innermost) from L1-resident 8 KB
// tables instead of 64-VGPR preloads; hr residual load moved after GEMM2.
// Peak live VGPR ~80 -> honestly fits the 128 cap of (256,4): no spills.
// sB/tB stride-33 (proven); oTb stride-136 u16, aliases sB. 4 blocks/CU.
// last==1: fused decoder to d_out.
// ---------------------------------------------------------------------------
union FfnSmem {
    unsigned int  sB[128 * 33];     // 16896 B, staged bf16 s tile [pix][ch-pair]
    unsigned short oTb[64 * 136];   // 17408 B, epilogue2 bf16 transpose tile
};

__global__ __launch_bounds__(256, 4) void k_ffn2m(const unsigned short* __restrict__ in, unsigned short* __restrict__ out,
                                                  const short* __restrict__ w1f, const float* __restrict__ b1v,
                                                  const short* __restrict__ w2f, const float* __restrict__ b2v,
                                                  const float* __restrict__ Wd, const float* __restrict__ bd,
                                                  float* __restrict__ dout, int last) {
    __shared__ __align__(16) FfnSmem u;
    __shared__ __align__(16) unsigned int tB[128 * 33];
    int t = threadIdx.x;
    int pixBase = blockIdx.x * 128;
    int lane15 = t & 15;
    int quad   = (t >> 4) & 3;
    int wv     = t >> 6;
    int k  = t >> 3;                           // staging channel pair 0..31
    int po = t & 7;                            // staging pixel oct (first half)
    int oct = t & 15;                          // store pixel oct 0..15
    int cg  = t >> 4;                          // store channel group 0..15

    // ---- s tile staging ----
    #pragma unroll
    for (int half = 0; half < 2; ++half) {
        int so = (po + half * 8) * 8;          // pixel base 0..120
        uint4 a = *(const uint4*)(in + (size_t)(2 * k) * NPIX + pixBase + so);
        uint4 b = *(const uint4*)(in + (size_t)(2 * k + 1) * NPIX + pixBase + so);
        unsigned int aw[4] = {a.x, a.y, a.z, a.w};
        unsigned int bw[4] = {b.x, b.y, b.z, b.w};
        #pragma unroll
        for (int i = 0; i < 4; ++i) {
            int pix = so + 2 * i;
            u.sB[pix * 33 + k]       = (aw[i] & 0xffffu) | (bw[i] << 16);
            u.sB[(pix + 1) * 33 + k] = (aw[i] >> 16) | (bw[i] & 0xffff0000u);
        }
    }

    f32x4 acc[2][4];
    #pragma unroll
    for (int ns = 0; ns < 2; ++ns)
        #pragma unroll
        for (int mt = 0; mt < 4; ++mt) acc[ns][mt] = (f32x4){0.f, 0.f, 0.f, 0.f};

    __syncthreads();

    // ---- GEMM1: 2-term, weights at use, ns innermost (each frag loaded once) ----
    #pragma unroll
    for (int kc = 0; kc < 2; ++kc) {
        union { unsigned int w[4]; short8 v; } bb0, bb1;
        int row0 = wv * 32 + lane15;
        int row1 = wv * 32 + 16 + lane15;
        #pragma unroll
        for (int i = 0; i < 4; ++i) {
            bb0.w[i] = u.sB[row0 * 33 + kc * 16 + quad * 4 + i];
            bb1.w[i] = u.sB[row1 * 33 + kc * 16 + quad * 4 + i];
        }
        #pragma unroll
        for (int mt = 0; mt < 4; ++mt) {
            int s8 = mt * 2 + kc;
            const short8* wp = (const short8*)(w1f + (((size_t)s8 * 64 + (t & 63)) << 4));
            short8 wh = wp[0], wl = wp[1];
            acc[0][mt] = MFMA16(wh, bb0.v, acc[0][mt]);
            acc[0][mt] = MFMA16(wl, bb0.v, acc[0][mt]);
            acc[1][mt] = MFMA16(wh, bb1.v, acc[1][mt]);
            acc[1][mt] = MFMA16(wl, bb1.v, acc[1][mt]);
        }
    }

    // ---- epilogue1: gelu -> bf16 pairs -> tB ----
    #pragma unroll
    for (int ns = 0; ns < 2; ++ns) {
        int row = wv * 32 + ns * 16 + lane15;
        #pragma unroll
        for (int mt = 0; mt < 4; ++mt) {
            const float* bp = b1v + mt * 16 + quad * 4;
            float g[4];
            #pragma unroll
            for (int r = 0; r < 4; ++r) g[r] = gelu_f(acc[ns][mt][r] + bp[r]);
            int cp = (mt * 16 + quad * 4) >> 1;
            tB[row * 33 + cp]     = (unsigned int)bf16_rne(g[0]) | ((unsigned int)bf16_rne(g[1]) << 16);
            tB[row * 33 + cp + 1] = (unsigned int)bf16_rne(g[2]) | ((unsigned int)bf16_rne(g[3]) << 16);
            acc[ns][mt] = (f32x4){0.f, 0.f, 0.f, 0.f};
        }
    }

    __syncthreads();   // tB visible; fences GEMM1 sB reads (oTb may alias)

    // ---- GEMM2: 2-term, weights at use ----
    #pragma unroll
    for (int kc = 0; kc < 2; ++kc) {
        union { unsigned int w[4]; short8 v; } bb0, bb1;
        int row0 = wv * 32 + lane15;
        int row1 = wv * 32 + 16 + lane15;
        #pragma unroll
        for (int i = 0; i < 4; ++i) {
            bb0.w[i] = tB[row0 * 33 + kc * 16 + quad * 4 + i];
            bb1.w[i] = tB[row1 * 33 + kc * 16 + quad * 4 + i];
        }
        #pragma unroll
        for (int mt = 0; mt < 4; ++mt) {
            int s8 = mt * 2 + kc;
            const short8* wp = (const short8*)(w2f + (((size_t)s8 * 64 + (t & 63)) << 4));
            short8 wh = wp[0], wl = wp[1];
            acc[0][mt] = MFMA16(wh, bb0.v, acc[0][mt]);
            acc[0][mt] = MFMA16(wl, bb0.v, acc[0][mt]);
            acc[1][mt] = MFMA16(wh, bb1.v, acc[1][mt]);
            acc[1][mt] = MFMA16(wl, bb1.v, acc[1][mt]);
        }
    }

    // ---- h residual load (moved here: latency hidden by epilogue2 VALU) ----
    uint4 hr[4];
    #pragma unroll
    for (int j = 0; j < 4; ++j) {
        int c = cg + 16 * j;
        hr[j] = *(const uint4*)(out + (size_t)c * NPIX + pixBase + oct * 8);
    }

    // ---- epilogue2: gelu -> bf16 oTb (aliases sB) ----
    #pragma unroll
    for (int ns = 0; ns < 2; ++ns) {
        int px = wv * 32 + ns * 16 + lane15;
        #pragma unroll
        for (int mt = 0; mt < 4; ++mt) {
            const float* bp = b2v + mt * 16 + quad * 4;
            #pragma unroll
            for (int r = 0; r < 4; ++r) {
                int c = mt * 16 + quad * 4 + r;
                u.oTb[c * 136 + px] = bf16_rne(gelu_f(acc[ns][mt][r] + bp[r]));
            }
        }
    }
    __syncthreads();

    if (!last) {
        // ---- h(bf16) += increment: (c,oct) units, uint4, full 256-B sectors/wave ----
        #pragma unroll
        for (int j = 0; j < 4; ++j) {
            int c = cg + 16 * j;
            uint4 gv = *(const uint4*)&u.oTb[c * 136 + oct * 8];
            unsigned int hw[4] = {hr[j].x, hr[j].y, hr[j].z, hr[j].w};
            unsigned int gw[4] = {gv.x, gv.y, gv.z, gv.w};
            uint4 o;
            unsigned int* op = &o.x;
            #pragma unroll
            for (int i = 0; i < 4; ++i) {
                float f0 = bf16_tof((unsigned short)(hw[i] & 0xffffu)) + bf16_tof((unsigned short)(gw[i] & 0xffffu));
                float f1 = bf16_tof((unsigned short)(hw[i] >> 16))     + bf16_tof((unsigned short)(gw[i] >> 16));
                op[i] = (unsigned int)bf16_rne(f0) | ((unsigned int)bf16_rne(f1) << 16);
            }
            *(uint4*)(out + (size_t)c * NPIX + pixBase + oct * 8) = o;
        }
    } else {
        // ---- fused decoder: dout = sum_c Wd[c]*(hres+gv) + bd (red aliases tB) ----
        float part[8] = {0.f,0.f,0.f,0.f,0.f,0.f,0.f,0.f};
        #pragma unroll
        for (int j = 0; j < 4; ++j) {
            int c = cg + 16 * j;
            float wd = Wd[c];
            uint4 gv = *(const uint4*)&u.oTb[c * 136 + oct * 8];
            unsigned int hw[4] = {hr[j].x, hr[j].y, hr[j].z, hr[j].w};
            unsigned int gw[4] = {gv.x, gv.y, gv.z, gv.w};
            #pragma unroll
            for (int i = 0; i < 4; ++i) {
                part[2*i]   += wd * (bf16_tof((unsigned short)(hw[i] & 0xffffu)) + bf16_tof((unsigned short)(gw[i] & 0xffffu)));
                part[2*i+1] += wd * (bf16_tof((unsigned short)(hw[i] >> 16))     + bf16_tof((unsigned short)(gw[i] >> 16)));
            }
        }
        float* red = (float*)tB;               // 16 grp x 132 stride x 4 B = 8448 B fits tB
        #pragma unroll
        for (int i = 0; i < 8; ++i)
            red[cg * 132 + oct * 8 + i] = part[i];
        __syncthreads();
        if (t < 128) {
            float sum = bd[0];
            #pragma unroll
            for (int gg = 0; gg < 16; ++gg)
                sum += red[gg * 132 + t];
            dout[pixBase + t] = sum;
        }
    }
}

extern "C" void kernel_launch(void* const* d_in, const int* in_sizes, int n_in,
                              void* d_out, int out_size, void* d_ws, size_t ws_size,
                              hipStream_t stream) {
    (void)in_sizes; (void)n_in; (void)out_size; (void)ws_size;
    const float* u   = (const float*)d_in[0];
    const float* xc  = (const float*)d_in[1];
    const float* We  = (const float*)d_in[2];
    const float* be  = (const float*)d_in[3];
    const float* W1  = (const float*)d_in[4];
    const float* b1  = (const float*)d_in[5];
    const float* W2  = (const float*)d_in[6];
    const float* b2  = (const float*)d_in[7];
    const float* Are = (const float*)d_in[8];
    const float* Aim = (const float*)d_in[9];
    const float* Wd  = (const float*)d_in[10];
    const float* bd  = (const float*)d_in[11];

    // workspace layout, ~93 MB used
    char* ws = (char*)d_ws;
    unsigned short* h = (unsigned short*)ws;                  // 32 MB (bf16)
    unsigned short* s = (unsigned short*)(ws + (size_t)33554432); // 32 MB (bf16)
    float* VfH = (float*)(ws + (size_t)67108864);             // 4 MB: [64][32][512]
    float* VfW = VfH + (size_t)1048576;                       // 4 MB
    unsigned int* VmH = (unsigned int*)(VfW + 1048576);       // 4 MB split-packed
    unsigned int* VmW = VmH + (size_t)1048576;                // 4 MB
    short* FbB = (short*)(VmW + 1048576);                     // 64 KB
    short* GbF = FbB + 32768;                                 // 64 KB
    short* Am  = GbF + 32768;                                 // 6 MB
    short* Wpk = Am  + (size_t)65536 * 48;                    // 128 KB

    k_setup<<<1312, 256, 0, stream>>>(W1, W2, Are, Aim, u, xc, We, be,
                                      FbB, GbF, Wpk, Am, h);

    for (int l = 0; l < 4; ++l) {
        k_fwd<<<dim3(64, 8, 2), 256, 0, stream>>>(h, FbB, VfH, VfW);
        k_mix2<<<512, 256, 0, stream>>>(VfH, VfW, Am + (size_t)(l * 2) * ASLAB, VmH, VmW);
        k_inv<<<dim3(8, 8, 64), 256, 0, stream>>>(VmW, VmH, GbF, s);
        k_ffn2m<<<2048, 256, 0, stream>>>(s, h,
                                          Wpk + (size_t)(l * 2 + 0) * 8192, b1 + (size_t)l * 64,
                                          Wpk + (size_t)(l * 2 + 1) * 8192, b2 + (size_t)l * 64,
                                          Wd, bd, (float*)d_out, (l == 3) ? 1 : 0);
    }
}